// Round 3
// baseline (720.299 us; speedup 1.0000x reference)
//
#include <hip/hip_runtime.h>
#include <math.h>

#define B_ 8192
#define F_ 16
#define V_ 50000
#define D_ 32
#define NE_ 3
#define EOD_ 512
#define M1_ 512
#define M2_ 256
#define M3_ 128
#define BE_ ((size_t)B_ * EOD_)

typedef __attribute__((ext_vector_type(8))) short short8;
typedef __attribute__((ext_vector_type(4))) float floatx4;
typedef __attribute__((ext_vector_type(4))) unsigned short us4;

__device__ __forceinline__ unsigned short f2bf(float f) {
    union { float f; unsigned u; } v; v.f = f;
    unsigned r = v.u + 0x7FFF + ((v.u >> 16) & 1);
    return (unsigned short)(r >> 16);
}
__device__ __forceinline__ float bf2f(unsigned short h) {
    union { unsigned u; float f; } v; v.u = (unsigned)h << 16;
    return v.f;
}
// async global->LDS, 16B per lane; LDS dest must be wave-uniform base + lane*16
__device__ __forceinline__ void gld16(const void* g, void* l) {
    __builtin_amdgcn_global_load_lds(
        (const __attribute__((address_space(1))) unsigned int*)g,
        (__attribute__((address_space(3))) unsigned int*)l, 16, 0, 0);
}
// load 3 bf16x8 slices (stride BE_), sum in f32, store 16B to LDS
__device__ __forceinline__ void sum3st(const unsigned short* p, unsigned short* l) {
    uint4 a = *(const uint4*)p;
    uint4 b = *(const uint4*)(p + BE_);
    uint4 c = *(const uint4*)(p + 2 * BE_);
    const unsigned short* pa = (const unsigned short*)&a;
    const unsigned short* pb = (const unsigned short*)&b;
    const unsigned short* pc = (const unsigned short*)&c;
    unsigned short r[8];
    #pragma unroll
    for (int j = 0; j < 8; j++) r[j] = f2bf(bf2f(pa[j]) + bf2f(pb[j]) + bf2f(pc[j]));
    *(uint4*)l = *(uint4*)r;
}

// ================= prep: weight transposes + gather + accumulator zeroing ================
__device__ __forceinline__ void wtrans_dev(const float* __restrict__ W,
    unsigned short* __restrict__ Wt, int K, int N, int bx, int by, int t,
    float (*tile)[33])
{
    int bn = bx * 32, bk = by * 32;
    int tx = t & 31, ty = t >> 5;   // 32 x 8
    #pragma unroll
    for (int i = 0; i < 32; i += 8)
        tile[ty + i][tx] = W[(size_t)(bk + ty + i) * N + bn + tx];
    __syncthreads();
    #pragma unroll
    for (int i = 0; i < 32; i += 8)
        Wt[(size_t)(bn + ty + i) * K + bk + tx] = f2bf(tile[tx][ty + i]);
}

__global__ __launch_bounds__(256) void prep_k(
    const int* __restrict__ x, const float* __restrict__ emb,
    const float* __restrict__ crossW, const float* __restrict__ mlp1W,
    const float* __restrict__ W1, const float* __restrict__ W2,
    unsigned short* __restrict__ WtC, unsigned short* __restrict__ Wt1,
    unsigned short* __restrict__ Wt2, unsigned short* __restrict__ esb,
    float* __restrict__ mbuf, float* __restrict__ psum)
{
    __shared__ float tile[32][33];
    int blk = blockIdx.x;
    int t = threadIdx.x;
    if (blk < 3072) {                                    // 12x 512x512 transposes
        int bx = blk & 15, by = (blk >> 4) & 15, mat = blk >> 8;
        const float* Wm = (mat < 9) ? crossW + (size_t)mat * 512 * 512
                                    : mlp1W + (size_t)(mat - 9) * 512 * 512;
        wtrans_dev(Wm, WtC + (size_t)mat * 512 * 512, 512, 512, bx, by, t, tile);
    } else if (blk < 3200) {                             // W1 512x256
        int r = blk - 3072;
        wtrans_dev(W1, Wt1, 512, 256, r & 7, r >> 3, t, tile);
    } else if (blk < 3232) {                             // W2 256x128
        int r = blk - 3200;
        wtrans_dev(W2, Wt2, 256, 128, r & 3, r >> 2, t, tile);
    } else if (blk < 9376) {                             // embedding gather
        int gid = (blk - 3232) * 256 + t;
        int d8 = gid & 3;
        int f  = (gid >> 2) & 15;
        int b  = (gid >> 6) & (B_ - 1);
        int e  = gid >> 19;
        int idx = x[b * F_ + f] + f * V_;
        const float4* src = (const float4*)(emb + ((size_t)e * F_ * V_ + idx) * D_) + d8 * 2;
        float4 v0 = src[0], v1 = src[1];
        unsigned short o[8];
        o[0] = f2bf(v0.x); o[1] = f2bf(v0.y); o[2] = f2bf(v0.z); o[3] = f2bf(v0.w);
        o[4] = f2bf(v1.x); o[5] = f2bf(v1.y); o[6] = f2bf(v1.z); o[7] = f2bf(v1.w);
        unsigned short* dst = esb + ((size_t)e * B_ + b) * EOD_ + f * D_ + d8 * 8;
        *(uint4*)dst = *(uint4*)o;
    } else if (blk < 9568) {                             // zero mbuf (48*1024 floats)
        int r = blk - 9376;
        mbuf[(size_t)r * 256 + t] = 0.f;
    } else {                                             // zero psum (96) + ticket (1)
        if (t < 128) psum[t] = 0.f;
    }
}

// ---------------- pair Gram accumulation (bf16 in, fp32 atomic accum) ----------------
__device__ void pairsum_dev(const unsigned short* es, float* m, int ablk, int t,
                            void* smemv)
{
    const int pi[3] = {1, 2, 2};
    const int pj[3] = {0, 0, 1};
    int pk = ablk % 48, by = ablk / 48;
    int pair = pk >> 4, k = pk & 15;
    const unsigned short* Ei = es + (size_t)pi[pair] * BE_ + k * D_;
    const unsigned short* Ej = es + (size_t)pj[pair] * BE_ + k * D_;
    int b0 = by * (B_ / 16);

    float (*sa)[32] = (float(*)[32])smemv;
    float (*sb)[32] = sa + 8;
    int d = t >> 3, e4 = (t & 7) * 4;
    int lr = t >> 5, lc = t & 31;
    float a0 = 0, a1 = 0, a2 = 0, a3 = 0;

    for (int bb = b0; bb < b0 + B_ / 16; bb += 8) {
        __syncthreads();
        sa[lr][lc] = bf2f(Ei[(size_t)(bb + lr) * EOD_ + lc]);
        sb[lr][lc] = bf2f(Ej[(size_t)(bb + lr) * EOD_ + lc]);
        __syncthreads();
        #pragma unroll
        for (int s2 = 0; s2 < 8; s2++) {
            float avv = sa[s2][d];
            float4 bvv = *(const float4*)&sb[s2][e4];
            a0 += avv * bvv.x; a1 += avv * bvv.y;
            a2 += avv * bvv.z; a3 += avv * bvv.w;
        }
    }
    float* dst = m + (size_t)pk * 1024 + d * 32 + e4;
    atomicAdd(dst + 0, a0); atomicAdd(dst + 1, a1);
    atomicAdd(dst + 2, a2); atomicAdd(dst + 3, a3);
}

// 32x32 singular values: one-sided Jacobi, one wave per matrix, register-resident.
// PHASE 0: Gram -> 3 sweeps -> state st.  (rides W1)
// PHASE 1: st -> 3 sweeps -> ranked sv -> atomic psum; last block computes reg loss.
template<int PHASE>
__device__ void svd_dev(const float* mg, float* st, float* psum, float* outf,
                        int ablk, int t, void* smemv)
{
    if (ablk >= 48 || t >= 64) return;
    int mat = ablk;
    int l = t;
    int col = l & 31, half = l >> 5;
    float a[16];
    if (PHASE == 0) {
        const float* src = mg + (size_t)mat * 1024 + half * 16 * 32 + col;
        #pragma unroll
        for (int j = 0; j < 16; j++) a[j] = src[j * 32];
    } else {
        #pragma unroll
        for (int j = 0; j < 16; j++) a[j] = st[(size_t)(mat * 16 + j) * 64 + l];
    }

    for (int sweep = 0; sweep < 3; sweep++) {
        for (int r = 0; r < 31; r++) {
            int partner, isp;
            if (col == 31) { partner = r; isp = 1; }
            else {
                int u = col - r; if (u < 0) u += 31;
                if (u == 0) { partner = 31; isp = 0; }
                else {
                    int v = 2 * r - col; v %= 31; if (v < 0) v += 31;
                    partner = v;
                    isp = (u <= 15) ? 1 : 0;
                }
            }
            int plane = half * 32 + partner;
            float b[16];
            #pragma unroll
            for (int j = 0; j < 16; j++) b[j] = __shfl(a[j], plane, 64);
            float own = 0.f, cross = 0.f, par = 0.f;
            #pragma unroll
            for (int j = 0; j < 16; j++) {
                own   += a[j] * a[j];
                cross += a[j] * b[j];
                par   += b[j] * b[j];
            }
            own   += __shfl_xor(own, 32);
            cross += __shfl_xor(cross, 32);
            par   += __shfl_xor(par, 32);
            float app = isp ? own : par;
            float aqq = isp ? par : own;
            float c = 1.f, s = 0.f;
            if (fabsf(cross) > 1e-12f) {
                float tau = (aqq - app) / (2.f * cross);
                float tt = (tau >= 0.f) ? 1.f / (tau + sqrtf(1.f + tau * tau))
                                        : 1.f / (tau - sqrtf(1.f + tau * tau));
                c = rsqrtf(1.f + tt * tt); s = tt * c;
            }
            float sgn = isp ? -s : s;
            #pragma unroll
            for (int j = 0; j < 16; j++) a[j] = c * a[j] + sgn * b[j];
        }
    }

    if (PHASE == 0) {
        #pragma unroll
        for (int j = 0; j < 16; j++) st[(size_t)(mat * 16 + j) * 64 + l] = a[j];
        return;
    }

    float nn = 0.f;
    #pragma unroll
    for (int j = 0; j < 16; j++) nn += a[j] * a[j];
    nn += __shfl_xor(nn, 32);
    float v = sqrtf(nn);

    float* ev = (float*)smemv;
    if (half == 0) ev[col] = v;
    // single wave: LDS ops complete in program order, no barrier needed
    if (half == 0) {
        int rank = 0;
        for (int o2 = 0; o2 < 32; o2++) {
            float w = ev[o2];
            if (w > v || (w == v && o2 < col)) rank++;
        }
        atomicAdd(&psum[(mat >> 4) * 32 + rank], v);
    }
    __threadfence();                       // drain psum adds before ticket
    unsigned old = 0;
    if (t == 0) old = atomicAdd((unsigned*)(psum + 96), 1u);
    old = (unsigned)__shfl((int)old, 0, 64);
    if (old == 47u) {                      // last block: reduce reg loss
        float x1 = atomicAdd(&psum[t], 0.f);         // device-coherent read
        float s1 = x1 * (1.f / 16.f);
        float val = s1 * s1;
        if (t < 32) {
            float x2 = atomicAdd(&psum[64 + t], 0.f);
            float s2 = x2 * (1.f / 16.f);
            val += s2 * s2;
        }
        #pragma unroll
        for (int off = 32; off > 0; off >>= 1) val += __shfl_down(val, off);
        if (t == 0) outf[B_] = 0.01f * val / 96.f;
    }
}

// ============ fused persistent cross x3 + mlp1: 32-row panel resident in LDS ============
// Panel [32][512] bf16 in LDS, XOR-swizzled (byte ^= (row&7)<<4 within row).
// Weights read straight from L2 into B-fragments -> no barriers in the K-loop,
// exactly one barrier per layer. x0 (=es) kept in registers in epilogue layout.
__device__ __forceinline__ void kloop512(const unsigned short* __restrict__ WtL,
    const unsigned short* pan, int wc, int lid, int quad, floatx4 (&acc)[2][8])
{
    #pragma unroll
    for (int i = 0; i < 2; i++)
        #pragma unroll
        for (int j = 0; j < 8; j++) acc[i][j] = {0.f, 0.f, 0.f, 0.f};
    const unsigned char* pb = (const unsigned char*)pan;
    int rsw = (lid & 7) << 4;
    #pragma unroll 2
    for (int k0 = 0; k0 < 512; k0 += 32) {
        int kb = (k0 + quad * 8) * 2;
        short8 a0 = *(const short8*)(pb + (lid << 10) + (kb ^ rsw));
        short8 a1 = *(const short8*)(pb + ((16 + lid) << 10) + (kb ^ rsw));
        #pragma unroll
        for (int j = 0; j < 8; j++) {
            short8 bfrag = *(const short8*)(WtL + (size_t)(wc + j * 16 + lid) * 512
                                            + k0 + quad * 8);
            acc[0][j] = __builtin_amdgcn_mfma_f32_16x16x32_bf16(bfrag, a0, acc[0][j], 0, 0, 0);
            acc[1][j] = __builtin_amdgcn_mfma_f32_16x16x32_bf16(bfrag, a1, acc[1][j], 0, 0, 0);
        }
    }
}

__global__ __launch_bounds__(256, 2) void fused_k(
    const unsigned short* __restrict__ esb,
    const unsigned short* __restrict__ WtC,
    const float* __restrict__ crossb,
    const float* __restrict__ mlp1b,
    unsigned short* __restrict__ B1,
    float* __restrict__ mbuf)
{
    __shared__ __align__(16) unsigned short panel[2][32 * 512];   // 2 x 32 KB
    int t = threadIdx.x;
    int blk = blockIdx.x;
    if (blk >= 768) { pairsum_dev(esb, mbuf, blk - 768, t, (void*)panel); return; }
    int e = blk >> 8, p = blk & 255;
    int w = t >> 6, lane = t & 63, quad = lane >> 4, lid = lane & 15;
    int wc = w * 128;
    const unsigned short* esP = esb + ((size_t)e * B_ + (size_t)p * 32) * 512;

    // stage es panel -> panel[0]; LDS linear dest, INVERSE-swizzled global source
    #pragma unroll
    for (int rnd = 0; rnd < 8; rnd++) {
        int L = rnd * 4096 + t * 16;
        int sw = ((L >> 10) & 7) << 4;
        gld16((const unsigned char*)esP + (L ^ sw),
              (unsigned char*)panel[0] + rnd * 4096 + w * 1024);
    }

    // x0 = es fragments in registers, exact epilogue layout
    us4 x0r[2][8];
    #pragma unroll
    for (int i = 0; i < 2; i++)
        #pragma unroll
        for (int j = 0; j < 8; j++)
            x0r[i][j] = *(const us4*)(esP + (size_t)(i * 16 + lid) * 512
                                      + wc + j * 16 + quad * 4);
    __syncthreads();

    floatx4 acc[2][8];
    int cur = 0;
    #pragma unroll 1
    for (int l = 0; l < 3; l++) {
        const unsigned short* WtL = WtC + (size_t)(e * 3 + l) * 262144;
        kloop512(WtL, panel[cur], wc, lid, quad, acc);
        const float* bias = crossb + (e * 3 + l) * 512;
        const unsigned char* pold = (const unsigned char*)panel[cur];
        unsigned char* pnew = (unsigned char*)panel[cur ^ 1];
        #pragma unroll
        for (int i = 0; i < 2; i++) {
            int row = i * 16 + lid;
            int rsw = (row & 7) << 4;
            #pragma unroll
            for (int j = 0; j < 8; j++) {
                int col = wc + j * 16 + quad * 4;
                int boff = (row << 10) + ((col << 1) ^ rsw);
                float4 bv = *(const float4*)(bias + col);
                us4 xlv = *(const us4*)(pold + boff);
                us4 xv = x0r[i][j];
                float v0 = bf2f(xv.x) * (acc[i][j][0] + bv.x) + bf2f(xlv.x);
                float v1 = bf2f(xv.y) * (acc[i][j][1] + bv.y) + bf2f(xlv.y);
                float v2 = bf2f(xv.z) * (acc[i][j][2] + bv.z) + bf2f(xlv.z);
                float v3 = bf2f(xv.w) * (acc[i][j][3] + bv.w) + bf2f(xlv.w);
                us4 o = { f2bf(v0), f2bf(v1), f2bf(v2), f2bf(v3) };
                *(us4*)(pnew + boff) = o;
            }
        }
        __syncthreads();
        cur ^= 1;
    }
    // mlp1: relu(.)/3 -> global B1 slice
    {
        const unsigned short* WtL = WtC + (size_t)(9 + e) * 262144;
        kloop512(WtL, panel[cur], wc, lid, quad, acc);
        const float* bias = mlp1b + e * 512;
        unsigned short* outp = B1 + ((size_t)e * B_ + (size_t)p * 32) * 512;
        #pragma unroll
        for (int i = 0; i < 2; i++) {
            int row = i * 16 + lid;
            #pragma unroll
            for (int j = 0; j < 8; j++) {
                int col = wc + j * 16 + quad * 4;
                float4 bv = *(const float4*)(bias + col);
                float v0 = fmaxf(acc[i][j][0] + bv.x, 0.f) * (1.f / 3.f);
                float v1 = fmaxf(acc[i][j][1] + bv.y, 0.f) * (1.f / 3.f);
                float v2 = fmaxf(acc[i][j][2] + bv.z, 0.f) * (1.f / 3.f);
                float v3 = fmaxf(acc[i][j][3] + bv.w, 0.f) * (1.f / 3.f);
                us4 o = { f2bf(v0), f2bf(v1), f2bf(v2), f2bf(v3) };
                *(us4*)(outp + (size_t)row * 512 + col) = o;
            }
        }
    }
}

// ---------------- bf16 MFMA GEMM, 128x128 tile, BK=64 (W1 / W2+final) ----------------
// MODE 2: v = relu(v)  (W1)
// MODE 3: relu -> LDS -> per-row dot with W3 + sigmoid -> outf (W2+final fused)
// ASUM 1: A-staging sums 3 bf16 slices (stride BE_)
// AUX: 0 none, 2 svd phase0, 3 svd phase1+reg  (blocks with z >= NZ)
template<int MODE, int AUX, int ASUM, int NZ>
__global__ __launch_bounds__(256) void gemm_k(
    const unsigned short* __restrict__ A,
    const unsigned short* __restrict__ Wt,
    const float* __restrict__ bias,
    unsigned short* __restrict__ outb,
    int M, int N, int K,
    float* __restrict__ mbuf, float* __restrict__ svst, float* __restrict__ psum,
    const float* __restrict__ W3, const float* __restrict__ b3,
    float* __restrict__ outf)
{
    __shared__ __align__(16) unsigned char smem[32768];
    int t = threadIdx.x;

    if (AUX && (int)blockIdx.z >= NZ) {
        int ablk = ((int)blockIdx.z - NZ) * (int)(gridDim.x * gridDim.y)
                 + (int)blockIdx.y * (int)gridDim.x + (int)blockIdx.x;
        if (AUX == 2) svd_dev<0>(mbuf, svst, psum, outf, ablk, t, smem);
        else          svd_dev<1>(mbuf, svst, psum, outf, ablk, t, smem);
        return;
    }

    unsigned short* As = (unsigned short*)smem;          // [128][64]
    unsigned short* Bs = As + 128 * 64;                  // [128][64]
    int w = t >> 6, lane = t & 63;
    int quad = lane >> 4, lid = lane & 15;
    int wr = (w & 1) * 64, wc = (w >> 1) * 64;
    int rowbase = blockIdx.y * 128, colbase = blockIdx.x * 128;

    int r4 = t >> 3;            // 0..31
    int c8 = (t & 7) * 8;
    const unsigned short* Ab = A  + (size_t)rowbase * K + c8;
    const unsigned short* Bb = Wt + (size_t)colbase * K + c8;
    unsigned short* lA = As + t * 8;
    unsigned short* lB = Bs + t * 8;

    floatx4 acc[4][4];
    #pragma unroll
    for (int i = 0; i < 4; i++)
        #pragma unroll
        for (int j = 0; j < 4; j++) acc[i][j] = {0.f, 0.f, 0.f, 0.f};

    for (int k0 = 0; k0 < K; k0 += 64) {
        if (k0) __syncthreads();
        #pragma unroll
        for (int i = 0; i < 4; i++) {
            size_t go = (size_t)(i * 32 + r4) * K + k0;
            if (ASUM) sum3st(Ab + go, lA + i * 2048);
            else      gld16(Ab + go, lA + i * 2048);
            gld16(Bb + go, lB + i * 2048);
        }
        __syncthreads();
        #pragma unroll
        for (int s = 0; s < 2; s++) {
            short8 af[4], bfr[4];
            #pragma unroll
            for (int i = 0; i < 4; i++) {
                af[i]  = *(const short8*)(As + (wr + i * 16 + lid) * 64 + s * 32 + quad * 8);
                bfr[i] = *(const short8*)(Bs + (wc + i * 16 + lid) * 64 + s * 32 + quad * 8);
            }
            #pragma unroll
            for (int i = 0; i < 4; i++)
                #pragma unroll
                for (int j = 0; j < 4; j++)
                    acc[i][j] = __builtin_amdgcn_mfma_f32_16x16x32_bf16(bfr[j], af[i], acc[i][j], 0, 0, 0);
        }
    }

    // Swapped C/D layout: row = wr + i*16 + lid, cols = wc + j*16 + quad*4 + rr
    if (MODE == 3) {
        __syncthreads();
        unsigned short* h2s = (unsigned short*)smem;   // [128][128] bf16, XOR-swizzled
        #pragma unroll
        for (int i = 0; i < 4; i++) {
            int rl = wr + i * 16 + lid;
            int sw = (rl & 7) << 3;
            #pragma unroll
            for (int j = 0; j < 4; j++) {
                int col0 = wc + j * 16 + quad * 4;
                float4 bv = *(const float4*)(bias + col0);
                float v0 = fmaxf(acc[i][j][0] + bv.x, 0.f);
                float v1 = fmaxf(acc[i][j][1] + bv.y, 0.f);
                float v2 = fmaxf(acc[i][j][2] + bv.z, 0.f);
                float v3 = fmaxf(acc[i][j][3] + bv.w, 0.f);
                us4 o = { f2bf(v0), f2bf(v1), f2bf(v2), f2bf(v3) };
                *(us4*)(h2s + (size_t)rl * 128 + (col0 ^ sw)) = o;
            }
        }
        __syncthreads();
        if (t < 128) {
            int sw = (t & 7) << 3;
            const unsigned short* hr = h2s + (size_t)t * 128;
            float pacc = 0.f;
            #pragma unroll
            for (int cc = 0; cc < 128; cc += 4) {
                us4 hv = *(const us4*)(hr + (cc ^ sw));
                float4 wv = *(const float4*)(W3 + cc);
                pacc += bf2f(hv.x) * wv.x + bf2f(hv.y) * wv.y
                      + bf2f(hv.z) * wv.z + bf2f(hv.w) * wv.w;
            }
            outf[rowbase + t] = 1.0f / (1.0f + expf(-(pacc + b3[0])));
        }
        return;
    }

    #pragma unroll
    for (int i = 0; i < 4; i++) {
        int row = rowbase + wr + i * 16 + lid;
        #pragma unroll
        for (int j = 0; j < 4; j++) {
            int col0 = colbase + wc + j * 16 + quad * 4;
            size_t off = (size_t)row * N + col0;
            float4 bv = *(const float4*)(bias + col0);
            float v0 = fmaxf(acc[i][j][0] + bv.x, 0.f);
            float v1 = fmaxf(acc[i][j][1] + bv.y, 0.f);
            float v2 = fmaxf(acc[i][j][2] + bv.z, 0.f);
            float v3 = fmaxf(acc[i][j][3] + bv.w, 0.f);
            us4 o = { f2bf(v0), f2bf(v1), f2bf(v2), f2bf(v3) };
            *(us4*)(outb + off) = o;
        }
    }
}

extern "C" void kernel_launch(void* const* d_in, const int* in_sizes, int n_in,
                              void* d_out, int out_size, void* d_ws, size_t ws_size,
                              hipStream_t stream)
{
    const int*   x      = (const int*)d_in[0];
    const float* emb    = (const float*)d_in[1];
    const float* crossW = (const float*)d_in[2];
    const float* crossb = (const float*)d_in[3];
    const float* mlp1W  = (const float*)d_in[4];
    const float* mlp1b  = (const float*)d_in[5];
    const float* W1     = (const float*)d_in[6];
    const float* b1     = (const float*)d_in[7];
    const float* W2     = (const float*)d_in[8];
    const float* b2     = (const float*)d_in[9];
    const float* W3     = (const float*)d_in[10];
    const float* b3     = (const float*)d_in[11];
    float* out = (float*)d_out;

    unsigned char* wsb = (unsigned char*)d_ws;
    size_t o = 0;
    auto alloc = [&](size_t bytes) -> void* {
        void* p = wsb + o; o += (bytes + 255) & ~(size_t)255; return p;
    };
    unsigned short* esb  = (unsigned short*)alloc(3 * BE_ * 2);
    unsigned short* B1b  = (unsigned short*)alloc(3 * BE_ * 2);
    unsigned short* WtC  = (unsigned short*)alloc((size_t)12 * 512 * 512 * 2);
    unsigned short* Wt1  = (unsigned short*)alloc((size_t)512 * 256 * 2);
    unsigned short* Wt2  = (unsigned short*)alloc((size_t)256 * 128 * 2);
    float*          mbuf = (float*)alloc(48 * 1024 * 4);
    float*          svst = (float*)alloc(48 * 16 * 64 * 4);
    float*          psum = (float*)alloc(128 * 4);       // 96 pair sums + ticket
    unsigned short* h1b  = esb;       // esb dead after fused; reuse for h1

    // prep: 12+2 weight transposes, gather, mbuf/psum zero — one dispatch
    prep_k<<<9569, 256, 0, stream>>>(x, emb, crossW, mlp1W, W1, W2,
                                     WtC, Wt1, Wt2, esb, mbuf, psum);

    // fused cross x3 + mlp1 (768 panel blocks) + pairsum aux (768 blocks)
    fused_k<<<1536, 256, 0, stream>>>(esb, WtC, crossb, mlp1b, B1b, mbuf);

    // W1: A = sum of 3 slices (fused sum3), relu  (+ svd phase-0 aux, z=1)
    gemm_k<2, 2, 1, 1><<<dim3(2, 64, 2), 256, 0, stream>>>(
        B1b, Wt1, b1, h1b, B_, M2_, M1_,
        mbuf, svst, psum, nullptr, nullptr, nullptr);
    // W2 + W3 + sigmoid fused  (+ svd phase-1 + reg-loss aux, z=1)
    gemm_k<3, 3, 0, 1><<<dim3(1, 64, 2), 256, 0, stream>>>(
        h1b, Wt2, b2, nullptr, B_, M3_, M2_,
        mbuf, svst, psum, W3, b3, out);
}

// Round 4
// 704.717 us; speedup vs baseline: 1.0221x; 1.0221x over previous
//
#include <hip/hip_runtime.h>
#include <math.h>

#define B_ 8192
#define F_ 16
#define V_ 50000
#define D_ 32
#define NE_ 3
#define EOD_ 512
#define M1_ 512
#define M2_ 256
#define M3_ 128
#define BE_ ((size_t)B_ * EOD_)

typedef __attribute__((ext_vector_type(8))) short short8;
typedef __attribute__((ext_vector_type(4))) float floatx4;
typedef __attribute__((ext_vector_type(4))) unsigned short us4;

__device__ __forceinline__ unsigned short f2bf(float f) {
    union { float f; unsigned u; } v; v.f = f;
    unsigned r = v.u + 0x7FFF + ((v.u >> 16) & 1);
    return (unsigned short)(r >> 16);
}
__device__ __forceinline__ float bf2f(unsigned short h) {
    union { unsigned u; float f; } v; v.u = (unsigned)h << 16;
    return v.f;
}
// async global->LDS, 16B per lane; LDS dest must be wave-uniform base + lane*16
__device__ __forceinline__ void gld16(const void* g, void* l) {
    __builtin_amdgcn_global_load_lds(
        (const __attribute__((address_space(1))) unsigned int*)g,
        (__attribute__((address_space(3))) unsigned int*)l, 16, 0, 0);
}
// load 3 bf16x8 slices (stride BE_), sum in f32, store 16B to LDS
__device__ __forceinline__ void sum3st(const unsigned short* p, unsigned short* l) {
    uint4 a = *(const uint4*)p;
    uint4 b = *(const uint4*)(p + BE_);
    uint4 c = *(const uint4*)(p + 2 * BE_);
    const unsigned short* pa = (const unsigned short*)&a;
    const unsigned short* pb = (const unsigned short*)&b;
    const unsigned short* pc = (const unsigned short*)&c;
    unsigned short r[8];
    #pragma unroll
    for (int j = 0; j < 8; j++) r[j] = f2bf(bf2f(pa[j]) + bf2f(pb[j]) + bf2f(pc[j]));
    *(uint4*)l = *(uint4*)r;
}

// ================= prep: weight transposes + gather + accumulator zeroing ================
__device__ __forceinline__ void wtrans_dev(const float* __restrict__ W,
    unsigned short* __restrict__ Wt, int K, int N, int bx, int by, int t,
    float (*tile)[33])
{
    int bn = bx * 32, bk = by * 32;
    int tx = t & 31, ty = t >> 5;   // 32 x 8
    #pragma unroll
    for (int i = 0; i < 32; i += 8)
        tile[ty + i][tx] = W[(size_t)(bk + ty + i) * N + bn + tx];
    __syncthreads();
    #pragma unroll
    for (int i = 0; i < 32; i += 8)
        Wt[(size_t)(bn + ty + i) * K + bk + tx] = f2bf(tile[tx][ty + i]);
}

__global__ __launch_bounds__(256) void prep_k(
    const int* __restrict__ x, const float* __restrict__ emb,
    const float* __restrict__ crossW, const float* __restrict__ mlp1W,
    const float* __restrict__ W1, const float* __restrict__ W2,
    unsigned short* __restrict__ WtC, unsigned short* __restrict__ Wt1,
    unsigned short* __restrict__ Wt2, unsigned short* __restrict__ esb,
    float* __restrict__ mbuf, float* __restrict__ psum)
{
    __shared__ float tile[32][33];
    int blk = blockIdx.x;
    int t = threadIdx.x;
    if (blk < 3072) {                                    // 12x 512x512 transposes
        int bx = blk & 15, by = (blk >> 4) & 15, mat = blk >> 8;
        const float* Wm = (mat < 9) ? crossW + (size_t)mat * 512 * 512
                                    : mlp1W + (size_t)(mat - 9) * 512 * 512;
        wtrans_dev(Wm, WtC + (size_t)mat * 512 * 512, 512, 512, bx, by, t, tile);
    } else if (blk < 3200) {                             // W1 512x256
        int r = blk - 3072;
        wtrans_dev(W1, Wt1, 512, 256, r & 7, r >> 3, t, tile);
    } else if (blk < 3232) {                             // W2 256x128
        int r = blk - 3200;
        wtrans_dev(W2, Wt2, 256, 128, r & 3, r >> 2, t, tile);
    } else if (blk < 9376) {                             // embedding gather
        int gid = (blk - 3232) * 256 + t;
        int d8 = gid & 3;
        int f  = (gid >> 2) & 15;
        int b  = (gid >> 6) & (B_ - 1);
        int e  = gid >> 19;
        int idx = x[b * F_ + f] + f * V_;
        const float4* src = (const float4*)(emb + ((size_t)e * F_ * V_ + idx) * D_) + d8 * 2;
        float4 v0 = src[0], v1 = src[1];
        unsigned short o[8];
        o[0] = f2bf(v0.x); o[1] = f2bf(v0.y); o[2] = f2bf(v0.z); o[3] = f2bf(v0.w);
        o[4] = f2bf(v1.x); o[5] = f2bf(v1.y); o[6] = f2bf(v1.z); o[7] = f2bf(v1.w);
        unsigned short* dst = esb + ((size_t)e * B_ + b) * EOD_ + f * D_ + d8 * 8;
        *(uint4*)dst = *(uint4*)o;
    } else if (blk < 9568) {                             // zero mbuf (48*1024 floats)
        int r = blk - 9376;
        mbuf[(size_t)r * 256 + t] = 0.f;
    } else {                                             // zero psum (96) + ticket (1)
        if (t < 128) psum[t] = 0.f;
    }
}

// ---------------- pair Gram accumulation (bf16 in, fp32 atomic accum) ----------------
__device__ void pairsum_dev(const unsigned short* es, float* m, int ablk, int t,
                            void* smemv)
{
    const int pi[3] = {1, 2, 2};
    const int pj[3] = {0, 0, 1};
    int pk = ablk % 48, by = ablk / 48;
    int pair = pk >> 4, k = pk & 15;
    const unsigned short* Ei = es + (size_t)pi[pair] * BE_ + k * D_;
    const unsigned short* Ej = es + (size_t)pj[pair] * BE_ + k * D_;
    int b0 = by * (B_ / 16);

    float (*sa)[32] = (float(*)[32])smemv;
    float (*sb)[32] = sa + 8;
    int d = t >> 3, e4 = (t & 7) * 4;
    int lr = t >> 5, lc = t & 31;
    float a0 = 0, a1 = 0, a2 = 0, a3 = 0;

    for (int bb = b0; bb < b0 + B_ / 16; bb += 8) {
        __syncthreads();
        sa[lr][lc] = bf2f(Ei[(size_t)(bb + lr) * EOD_ + lc]);
        sb[lr][lc] = bf2f(Ej[(size_t)(bb + lr) * EOD_ + lc]);
        __syncthreads();
        #pragma unroll
        for (int s2 = 0; s2 < 8; s2++) {
            float avv = sa[s2][d];
            float4 bvv = *(const float4*)&sb[s2][e4];
            a0 += avv * bvv.x; a1 += avv * bvv.y;
            a2 += avv * bvv.z; a3 += avv * bvv.w;
        }
    }
    float* dst = m + (size_t)pk * 1024 + d * 32 + e4;
    atomicAdd(dst + 0, a0); atomicAdd(dst + 1, a1);
    atomicAdd(dst + 2, a2); atomicAdd(dst + 3, a3);
}

// 32x32 singular values: one-sided Jacobi, one wave per matrix, register-resident.
// PHASE 0: Gram -> 3 sweeps -> state st.  (rides W1)
// PHASE 1: st -> 3 sweeps -> ranked sv -> atomic psum; last block computes reg loss.
template<int PHASE>
__device__ void svd_dev(const float* mg, float* st, float* psum, float* outf,
                        int ablk, int t, void* smemv)
{
    if (ablk >= 48 || t >= 64) return;
    int mat = ablk;
    int l = t;
    int col = l & 31, half = l >> 5;
    float a[16];
    if (PHASE == 0) {
        const float* src = mg + (size_t)mat * 1024 + half * 16 * 32 + col;
        #pragma unroll
        for (int j = 0; j < 16; j++) a[j] = src[j * 32];
    } else {
        #pragma unroll
        for (int j = 0; j < 16; j++) a[j] = st[(size_t)(mat * 16 + j) * 64 + l];
    }

    for (int sweep = 0; sweep < 3; sweep++) {
        for (int r = 0; r < 31; r++) {
            int partner, isp;
            if (col == 31) { partner = r; isp = 1; }
            else {
                int u = col - r; if (u < 0) u += 31;
                if (u == 0) { partner = 31; isp = 0; }
                else {
                    int v = 2 * r - col; v %= 31; if (v < 0) v += 31;
                    partner = v;
                    isp = (u <= 15) ? 1 : 0;
                }
            }
            int plane = half * 32 + partner;
            float b[16];
            #pragma unroll
            for (int j = 0; j < 16; j++) b[j] = __shfl(a[j], plane, 64);
            float own = 0.f, cross = 0.f, par = 0.f;
            #pragma unroll
            for (int j = 0; j < 16; j++) {
                own   += a[j] * a[j];
                cross += a[j] * b[j];
                par   += b[j] * b[j];
            }
            own   += __shfl_xor(own, 32);
            cross += __shfl_xor(cross, 32);
            par   += __shfl_xor(par, 32);
            float app = isp ? own : par;
            float aqq = isp ? par : own;
            float c = 1.f, s = 0.f;
            if (fabsf(cross) > 1e-12f) {
                float tau = (aqq - app) / (2.f * cross);
                float tt = (tau >= 0.f) ? 1.f / (tau + sqrtf(1.f + tau * tau))
                                        : 1.f / (tau - sqrtf(1.f + tau * tau));
                c = rsqrtf(1.f + tt * tt); s = tt * c;
            }
            float sgn = isp ? -s : s;
            #pragma unroll
            for (int j = 0; j < 16; j++) a[j] = c * a[j] + sgn * b[j];
        }
    }

    if (PHASE == 0) {
        #pragma unroll
        for (int j = 0; j < 16; j++) st[(size_t)(mat * 16 + j) * 64 + l] = a[j];
        return;
    }

    float nn = 0.f;
    #pragma unroll
    for (int j = 0; j < 16; j++) nn += a[j] * a[j];
    nn += __shfl_xor(nn, 32);
    float v = sqrtf(nn);

    float* ev = (float*)smemv;
    if (half == 0) ev[col] = v;
    // single wave: LDS ops complete in program order, no barrier needed
    if (half == 0) {
        int rank = 0;
        for (int o2 = 0; o2 < 32; o2++) {
            float w = ev[o2];
            if (w > v || (w == v && o2 < col)) rank++;
        }
        atomicAdd(&psum[(mat >> 4) * 32 + rank], v);
    }
    __threadfence();                       // drain psum adds before ticket
    unsigned old = 0;
    if (t == 0) old = atomicAdd((unsigned*)(psum + 96), 1u);
    old = (unsigned)__shfl((int)old, 0, 64);
    if (old == 47u) {                      // last block: reduce reg loss
        float x1 = atomicAdd(&psum[t], 0.f);         // device-coherent read
        float s1 = x1 * (1.f / 16.f);
        float val = s1 * s1;
        if (t < 32) {
            float x2 = atomicAdd(&psum[64 + t], 0.f);
            float s2 = x2 * (1.f / 16.f);
            val += s2 * s2;
        }
        #pragma unroll
        for (int off = 32; off > 0; off >>= 1) val += __shfl_down(val, off);
        if (t == 0) outf[B_] = 0.01f * val / 96.f;
    }
}

// ============ fused persistent cross x3 + mlp1: 32-row panel resident in LDS ============
// SINGLE panel [32][512] bf16 in LDS (32 KB -> 4 blocks/CU), XOR-swizzled
// (byte ^= (row&7)<<4 within row). Residual update is IN PLACE: each thread
// reads/writes only its own fragment addresses; barriers separate the kloop's
// whole-panel reads from the owner-partitioned writes.
// Weights read straight from L2 into B-fragments -> no barriers in the K-loop.
__device__ __forceinline__ void kloop512(const unsigned short* __restrict__ WtL,
    const unsigned short* pan, int wc, int lid, int quad, floatx4 (&acc)[2][8])
{
    #pragma unroll
    for (int i = 0; i < 2; i++)
        #pragma unroll
        for (int j = 0; j < 8; j++) acc[i][j] = {0.f, 0.f, 0.f, 0.f};
    const unsigned char* pb = (const unsigned char*)pan;
    int rsw = (lid & 7) << 4;
    #pragma unroll 2
    for (int k0 = 0; k0 < 512; k0 += 32) {
        int kb = (k0 + quad * 8) * 2;
        short8 a0 = *(const short8*)(pb + (lid << 10) + (kb ^ rsw));
        short8 a1 = *(const short8*)(pb + ((16 + lid) << 10) + (kb ^ rsw));
        #pragma unroll
        for (int j = 0; j < 8; j++) {
            short8 bfrag = *(const short8*)(WtL + (size_t)(wc + j * 16 + lid) * 512
                                            + k0 + quad * 8);
            acc[0][j] = __builtin_amdgcn_mfma_f32_16x16x32_bf16(bfrag, a0, acc[0][j], 0, 0, 0);
            acc[1][j] = __builtin_amdgcn_mfma_f32_16x16x32_bf16(bfrag, a1, acc[1][j], 0, 0, 0);
        }
    }
}

__global__ __launch_bounds__(256, 4) void fused_k(
    const unsigned short* __restrict__ esb,
    const unsigned short* __restrict__ WtC,
    const float* __restrict__ crossb,
    const float* __restrict__ mlp1b,
    unsigned short* __restrict__ B1,
    float* __restrict__ mbuf)
{
    __shared__ __align__(16) unsigned short panel[32 * 512];   // 32 KB
    int t = threadIdx.x;
    int blk = blockIdx.x;
    if (blk >= 768) { pairsum_dev(esb, mbuf, blk - 768, t, (void*)panel); return; }
    int e = blk >> 8, p = blk & 255;
    int w = t >> 6, lane = t & 63, quad = lane >> 4, lid = lane & 15;
    int wc = w * 128;
    const unsigned short* esP = esb + ((size_t)e * B_ + (size_t)p * 32) * 512;

    // stage es panel -> panel; LDS linear dest, INVERSE-swizzled global source
    #pragma unroll
    for (int rnd = 0; rnd < 8; rnd++) {
        int L = rnd * 4096 + t * 16;
        int sw = ((L >> 10) & 7) << 4;
        gld16((const unsigned char*)esP + (L ^ sw),
              (unsigned char*)panel + rnd * 4096 + w * 1024);
    }

    // x0 = es fragments in registers, exact epilogue layout
    us4 x0r[2][8];
    #pragma unroll
    for (int i = 0; i < 2; i++)
        #pragma unroll
        for (int j = 0; j < 8; j++)
            x0r[i][j] = *(const us4*)(esP + (size_t)(i * 16 + lid) * 512
                                      + wc + j * 16 + quad * 4);
    __syncthreads();

    floatx4 acc[2][8];
    #pragma unroll 1
    for (int l = 0; l < 3; l++) {
        const unsigned short* WtL = WtC + (size_t)(e * 3 + l) * 262144;
        kloop512(WtL, panel, wc, lid, quad, acc);
        __syncthreads();                       // kloop reads done before in-place write
        const float* bias = crossb + (e * 3 + l) * 512;
        unsigned char* pby = (unsigned char*)panel;
        #pragma unroll
        for (int i = 0; i < 2; i++) {
            int row = i * 16 + lid;
            int rsw = (row & 7) << 4;
            #pragma unroll
            for (int j = 0; j < 8; j++) {
                int col = wc + j * 16 + quad * 4;
                int boff = (row << 10) + ((col << 1) ^ rsw);
                float4 bv = *(const float4*)(bias + col);
                us4 xlv = *(const us4*)(pby + boff);
                us4 xv = x0r[i][j];
                float v0 = bf2f(xv.x) * (acc[i][j][0] + bv.x) + bf2f(xlv.x);
                float v1 = bf2f(xv.y) * (acc[i][j][1] + bv.y) + bf2f(xlv.y);
                float v2 = bf2f(xv.z) * (acc[i][j][2] + bv.z) + bf2f(xlv.z);
                float v3 = bf2f(xv.w) * (acc[i][j][3] + bv.w) + bf2f(xlv.w);
                us4 o = { f2bf(v0), f2bf(v1), f2bf(v2), f2bf(v3) };
                *(us4*)(pby + boff) = o;
            }
        }
        __syncthreads();                       // writes visible before next kloop
    }
    // mlp1: relu(.)/3 -> global B1 slice (reads panel only; no barrier needed after)
    {
        const unsigned short* WtL = WtC + (size_t)(9 + e) * 262144;
        kloop512(WtL, panel, wc, lid, quad, acc);
        const float* bias = mlp1b + e * 512;
        unsigned short* outp = B1 + ((size_t)e * B_ + (size_t)p * 32) * 512;
        #pragma unroll
        for (int i = 0; i < 2; i++) {
            int row = i * 16 + lid;
            #pragma unroll
            for (int j = 0; j < 8; j++) {
                int col = wc + j * 16 + quad * 4;
                float4 bv = *(const float4*)(bias + col);
                float v0 = fmaxf(acc[i][j][0] + bv.x, 0.f) * (1.f / 3.f);
                float v1 = fmaxf(acc[i][j][1] + bv.y, 0.f) * (1.f / 3.f);
                float v2 = fmaxf(acc[i][j][2] + bv.z, 0.f) * (1.f / 3.f);
                float v3 = fmaxf(acc[i][j][3] + bv.w, 0.f) * (1.f / 3.f);
                us4 o = { f2bf(v0), f2bf(v1), f2bf(v2), f2bf(v3) };
                *(us4*)(outp + (size_t)row * 512 + col) = o;
            }
        }
    }
}

// ---------------- bf16 MFMA GEMM, 128x128 tile, BK=64 (W1 / W2+final) ----------------
// MODE 2: v = relu(v)  (W1)
// MODE 3: relu -> LDS -> per-row dot with W3 + sigmoid -> outf (W2+final fused)
// ASUM 1: A-staging sums 3 bf16 slices (stride BE_)
// AUX: 0 none, 2 svd phase0, 3 svd phase1+reg  (blocks with z >= NZ)
template<int MODE, int AUX, int ASUM, int NZ>
__global__ __launch_bounds__(256) void gemm_k(
    const unsigned short* __restrict__ A,
    const unsigned short* __restrict__ Wt,
    const float* __restrict__ bias,
    unsigned short* __restrict__ outb,
    int M, int N, int K,
    float* __restrict__ mbuf, float* __restrict__ svst, float* __restrict__ psum,
    const float* __restrict__ W3, const float* __restrict__ b3,
    float* __restrict__ outf)
{
    __shared__ __align__(16) unsigned char smem[32768];
    int t = threadIdx.x;

    if (AUX && (int)blockIdx.z >= NZ) {
        int ablk = ((int)blockIdx.z - NZ) * (int)(gridDim.x * gridDim.y)
                 + (int)blockIdx.y * (int)gridDim.x + (int)blockIdx.x;
        if (AUX == 2) svd_dev<0>(mbuf, svst, psum, outf, ablk, t, smem);
        else          svd_dev<1>(mbuf, svst, psum, outf, ablk, t, smem);
        return;
    }

    unsigned short* As = (unsigned short*)smem;          // [128][64]
    unsigned short* Bs = As + 128 * 64;                  // [128][64]
    int w = t >> 6, lane = t & 63;
    int quad = lane >> 4, lid = lane & 15;
    int wr = (w & 1) * 64, wc = (w >> 1) * 64;
    int rowbase = blockIdx.y * 128, colbase = blockIdx.x * 128;

    int r4 = t >> 3;            // 0..31
    int c8 = (t & 7) * 8;
    const unsigned short* Ab = A  + (size_t)rowbase * K + c8;
    const unsigned short* Bb = Wt + (size_t)colbase * K + c8;
    unsigned short* lA = As + t * 8;
    unsigned short* lB = Bs + t * 8;

    floatx4 acc[4][4];
    #pragma unroll
    for (int i = 0; i < 4; i++)
        #pragma unroll
        for (int j = 0; j < 4; j++) acc[i][j] = {0.f, 0.f, 0.f, 0.f};

    for (int k0 = 0; k0 < K; k0 += 64) {
        if (k0) __syncthreads();
        #pragma unroll
        for (int i = 0; i < 4; i++) {
            size_t go = (size_t)(i * 32 + r4) * K + k0;
            if (ASUM) sum3st(Ab + go, lA + i * 2048);
            else      gld16(Ab + go, lA + i * 2048);
            gld16(Bb + go, lB + i * 2048);
        }
        __syncthreads();
        #pragma unroll
        for (int s = 0; s < 2; s++) {
            short8 af[4], bfr[4];
            #pragma unroll
            for (int i = 0; i < 4; i++) {
                af[i]  = *(const short8*)(As + (wr + i * 16 + lid) * 64 + s * 32 + quad * 8);
                bfr[i] = *(const short8*)(Bs + (wc + i * 16 + lid) * 64 + s * 32 + quad * 8);
            }
            #pragma unroll
            for (int i = 0; i < 4; i++)
                #pragma unroll
                for (int j = 0; j < 4; j++)
                    acc[i][j] = __builtin_amdgcn_mfma_f32_16x16x32_bf16(bfr[j], af[i], acc[i][j], 0, 0, 0);
        }
    }

    // Swapped C/D layout: row = wr + i*16 + lid, cols = wc + j*16 + quad*4 + rr
    if (MODE == 3) {
        __syncthreads();
        unsigned short* h2s = (unsigned short*)smem;   // [128][128] bf16, XOR-swizzled
        #pragma unroll
        for (int i = 0; i < 4; i++) {
            int rl = wr + i * 16 + lid;
            int sw = (rl & 7) << 3;
            #pragma unroll
            for (int j = 0; j < 4; j++) {
                int col0 = wc + j * 16 + quad * 4;
                float4 bv = *(const float4*)(bias + col0);
                float v0 = fmaxf(acc[i][j][0] + bv.x, 0.f);
                float v1 = fmaxf(acc[i][j][1] + bv.y, 0.f);
                float v2 = fmaxf(acc[i][j][2] + bv.z, 0.f);
                float v3 = fmaxf(acc[i][j][3] + bv.w, 0.f);
                us4 o = { f2bf(v0), f2bf(v1), f2bf(v2), f2bf(v3) };
                *(us4*)(h2s + (size_t)rl * 128 + (col0 ^ sw)) = o;
            }
        }
        __syncthreads();
        if (t < 128) {
            int sw = (t & 7) << 3;
            const unsigned short* hr = h2s + (size_t)t * 128;
            float pacc = 0.f;
            #pragma unroll
            for (int cc = 0; cc < 128; cc += 4) {
                us4 hv = *(const us4*)(hr + (cc ^ sw));
                float4 wv = *(const float4*)(W3 + cc);
                pacc += bf2f(hv.x) * wv.x + bf2f(hv.y) * wv.y
                      + bf2f(hv.z) * wv.z + bf2f(hv.w) * wv.w;
            }
            outf[rowbase + t] = 1.0f / (1.0f + expf(-(pacc + b3[0])));
        }
        return;
    }

    #pragma unroll
    for (int i = 0; i < 4; i++) {
        int row = rowbase + wr + i * 16 + lid;
        #pragma unroll
        for (int j = 0; j < 4; j++) {
            int col0 = colbase + wc + j * 16 + quad * 4;
            size_t off = (size_t)row * N + col0;
            float4 bv = *(const float4*)(bias + col0);
            float v0 = fmaxf(acc[i][j][0] + bv.x, 0.f);
            float v1 = fmaxf(acc[i][j][1] + bv.y, 0.f);
            float v2 = fmaxf(acc[i][j][2] + bv.z, 0.f);
            float v3 = fmaxf(acc[i][j][3] + bv.w, 0.f);
            us4 o = { f2bf(v0), f2bf(v1), f2bf(v2), f2bf(v3) };
            *(us4*)(outb + off) = o;
        }
    }
}

extern "C" void kernel_launch(void* const* d_in, const int* in_sizes, int n_in,
                              void* d_out, int out_size, void* d_ws, size_t ws_size,
                              hipStream_t stream)
{
    const int*   x      = (const int*)d_in[0];
    const float* emb    = (const float*)d_in[1];
    const float* crossW = (const float*)d_in[2];
    const float* crossb = (const float*)d_in[3];
    const float* mlp1W  = (const float*)d_in[4];
    const float* mlp1b  = (const float*)d_in[5];
    const float* W1     = (const float*)d_in[6];
    const float* b1     = (const float*)d_in[7];
    const float* W2     = (const float*)d_in[8];
    const float* b2     = (const float*)d_in[9];
    const float* W3     = (const float*)d_in[10];
    const float* b3     = (const float*)d_in[11];
    float* out = (float*)d_out;

    unsigned char* wsb = (unsigned char*)d_ws;
    size_t o = 0;
    auto alloc = [&](size_t bytes) -> void* {
        void* p = wsb + o; o += (bytes + 255) & ~(size_t)255; return p;
    };
    unsigned short* esb  = (unsigned short*)alloc(3 * BE_ * 2);
    unsigned short* B1b  = (unsigned short*)alloc(3 * BE_ * 2);
    unsigned short* WtC  = (unsigned short*)alloc((size_t)12 * 512 * 512 * 2);
    unsigned short* Wt1  = (unsigned short*)alloc((size_t)512 * 256 * 2);
    unsigned short* Wt2  = (unsigned short*)alloc((size_t)256 * 128 * 2);
    float*          mbuf = (float*)alloc(48 * 1024 * 4);
    float*          svst = (float*)alloc(48 * 16 * 64 * 4);
    float*          psum = (float*)alloc(128 * 4);       // 96 pair sums + ticket
    unsigned short* h1b  = esb;       // esb dead after fused; reuse for h1

    // prep: 12+2 weight transposes, gather, mbuf/psum zero — one dispatch
    prep_k<<<9569, 256, 0, stream>>>(x, emb, crossW, mlp1W, W1, W2,
                                     WtC, Wt1, Wt2, esb, mbuf, psum);

    // fused cross x3 + mlp1 (768 panel blocks) + pairsum aux (768 blocks)
    fused_k<<<1536, 256, 0, stream>>>(esb, WtC, crossb, mlp1b, B1b, mbuf);

    // W1: A = sum of 3 slices (fused sum3), relu  (+ svd phase-0 aux, z=1)
    gemm_k<2, 2, 1, 1><<<dim3(2, 64, 2), 256, 0, stream>>>(
        B1b, Wt1, b1, h1b, B_, M2_, M1_,
        mbuf, svst, psum, nullptr, nullptr, nullptr);
    // W2 + W3 + sigmoid fused  (+ svd phase-1 + reg-loss aux, z=1)
    gemm_k<3, 3, 0, 1><<<dim3(1, 64, 2), 256, 0, stream>>>(
        h1b, Wt2, b2, nullptr, B_, M3_, M2_,
        mbuf, svst, psum, W3, b3, out);
}